// Round 4
// baseline (621.026 us; speedup 1.0000x reference)
//
#include <hip/hip_runtime.h>
#include <stdint.h>
#include <stddef.h>

// Problem constants
#define DDIM 4096
#define MROWS 8192          // 4 * 2048
#define RANK 8

typedef __attribute__((ext_vector_type(8))) short bf16x8;    // 8 bf16 = 4 VGPRs
typedef __attribute__((ext_vector_type(4))) float f32x4;
typedef __attribute__((ext_vector_type(16))) float f32x16;
typedef __attribute__((ext_vector_type(8))) unsigned short u16x8;

// RNE float -> bf16 bits
__device__ __forceinline__ unsigned short f2bf(float f) {
  union { float f; unsigned int u; } c; c.f = f;
  unsigned int u = c.u + 0x7fffu + ((c.u >> 16) & 1u);
  return (unsigned short)(u >> 16);
}

// ---------------- Kernel 1: x fp32 -> bf16 (32B load / 16B store per thread) ----
__global__ void convert_x_kernel(const float4* __restrict__ x, u16x8* __restrict__ out) {
  int idx = blockIdx.x * 256 + threadIdx.x;
  float4 v0 = x[2 * idx];
  float4 v1 = x[2 * idx + 1];
  u16x8 o;
  o[0] = f2bf(v0.x); o[1] = f2bf(v0.y); o[2] = f2bf(v0.z); o[3] = f2bf(v0.w);
  o[4] = f2bf(v1.x); o[5] = f2bf(v1.y); o[6] = f2bf(v1.z); o[7] = f2bf(v1.w);
  out[idx] = o;
}

// ---------------- Kernel 2: fold SRHT into A2 / B2t via FWHT (1024 thr) --------
__global__ __launch_bounds__(1024) void srht_fold_kernel(
    const float* __restrict__ A, const float* __restrict__ Bm,
    const float* __restrict__ in_signs, const float* __restrict__ out_signs,
    const int* __restrict__ in_perm, const int* __restrict__ out_perm,
    float* __restrict__ A2, float* __restrict__ B2t) {
  __shared__ float buf[DDIM];
  const int tid = threadIdx.x;
  const int b = blockIdx.x;
  if (b < RANK) {
    const int r = b;
    for (int j = tid; j < DDIM; j += 1024) {
      int p = in_perm[j];
      buf[j] = in_signs[p] * A[r * DDIM + p];
    }
  } else {
    const int r = b - RANK;
    for (int j = tid; j < DDIM; j += 1024) {
      int p = out_perm[j];
      buf[j] = out_signs[p] * Bm[p * RANK + r];
    }
  }
  __syncthreads();
  for (int h = 1; h < DDIM; h <<= 1) {
    for (int p = tid; p < DDIM / 2; p += 1024) {
      int j = p & (h - 1);
      int i0 = ((p - j) << 1) + j;
      int i1 = i0 + h;
      float a = buf[i0], c = buf[i1];
      buf[i0] = a + c;
      buf[i1] = a - c;
    }
    __syncthreads();
  }
  const float scale = (b < RANK) ? (1.0f / 64.0f) : (2.0f / 64.0f);  // 2/64 folds SCALE
  float* dst = (b < RANK) ? (A2 + b * DDIM) : (B2t + (b - RANK) * DDIM);
  for (int j = tid; j < DDIM; j += 1024) dst[j] = buf[j] * scale;
}

// ---------------- Kernel 3: Weff = bf16(W + B2*A2) ----------------
__global__ void weff_kernel(const float4* __restrict__ W, const float* __restrict__ A2,
                            const float* __restrict__ B2t, u16x8* __restrict__ Weff) {
  int idx = blockIdx.x * 256 + threadIdx.x;  // 8-float groups: 4096*512
  int o = idx >> 9;                          // output row
  int c8 = idx & 511;                        // 8-float group within row
  float4 w0 = W[2 * idx];
  float4 w1 = W[2 * idx + 1];
#pragma unroll
  for (int r = 0; r < RANK; ++r) {
    float s = B2t[r * DDIM + o];
    const float4* av = (const float4*)(A2 + r * DDIM) + 2 * c8;
    float4 a0 = av[0], a1 = av[1];
    w0.x += s * a0.x; w0.y += s * a0.y; w0.z += s * a0.z; w0.w += s * a0.w;
    w1.x += s * a1.x; w1.y += s * a1.y; w1.z += s * a1.z; w1.w += s * a1.w;
  }
  u16x8 u;
  u[0] = f2bf(w0.x); u[1] = f2bf(w0.y); u[2] = f2bf(w0.z); u[3] = f2bf(w0.w);
  u[4] = f2bf(w1.x); u[5] = f2bf(w1.y); u[6] = f2bf(w1.z); u[7] = f2bf(w1.w);
  Weff[idx] = u;
}

// ---------------- Kernel 4: C = A * B^T + bias, producer/consumer waves --------
// 512 threads = 8 waves. Waves 0-3: compute 128x128 (2x2 of 32x32x16 MFMA each).
// Waves 4-7: stage tile k+1 into the other LDS buffer via global_load_lds.
// Double-buffered LDS (2 x 32 KB). One barrier per K-iter; only the producer
// path has outstanding global loads, so its vmcnt(0) drain overlaps a full
// iteration of consumer MFMA instead of stalling all waves (the m97 plateau).
// Swizzle: slot s of row r holds global chunk c = s ^ swz(r),
// swz(r) = (r&7) ^ ((r>>3)&3)  -- conflict-free for 32-row fragment reads (R3).
__device__ __forceinline__ void async_copy16(const unsigned short* g, unsigned short* l) {
  __builtin_amdgcn_global_load_lds(
      (const __attribute__((address_space(1))) unsigned int*)g,
      (__attribute__((address_space(3))) unsigned int*)l, 16, 0, 0);
}

__global__ __launch_bounds__(512, 4) void gemm_bt_kernel(
    const unsigned short* __restrict__ Ab,   // M x K bf16 (x)
    const unsigned short* __restrict__ Bb,   // N x K bf16 (Weff)
    const float* __restrict__ bias,
    float* __restrict__ C) {                 // M x N fp32
  constexpr int K = 4096, N = 4096;
  constexpr int BUF = 128 * 64;              // shorts per buffer
  __shared__ unsigned short As[2 * BUF];
  __shared__ unsigned short Bs[2 * BUF];

  const int tid = threadIdx.x;
  const int wid = tid >> 6;
  const int pid = blockIdx.x;

  // grouped ordering for L2 reuse (GROUP_M = 8)
  const int GRID_N = 32;
  const int grpsz = 8 * GRID_N;            // 256
  const int group = pid / grpsz;
  const int lpid = pid % grpsz;
  const int m_blk = group * 8 + (lpid & 7);
  const int n_blk = lpid >> 3;
  const int mBase = m_blk * 128;
  const int nBase = n_blk * 128;

  if (wid >= 4) {
    // ---------------- producer waves ----------------
    const int pt = tid & 255;
    const int sr = pt >> 3;                              // row within round
    const int swz_s = (sr & 7) ^ ((sr >> 3) & 3);
    const int sc = (pt & 7) ^ swz_s;                     // global chunk to fetch
    const unsigned short* ga[4];
    const unsigned short* gb[4];
#pragma unroll
    for (int j = 0; j < 4; ++j) {
      ga[j] = Ab + (size_t)(mBase + j * 32 + sr) * K + sc * 8;
      gb[j] = Bb + (size_t)(nBase + j * 32 + sr) * K + sc * 8;
    }
    unsigned short* lA = As + pt * 8;
    unsigned short* lB = Bs + pt * 8;

    // stage tile 0 into buffer 0
#pragma unroll
    for (int j = 0; j < 4; ++j) async_copy16(ga[j], lA + j * 2048);
#pragma unroll
    for (int j = 0; j < 4; ++j) async_copy16(gb[j], lB + j * 2048);
#pragma unroll
    for (int j = 0; j < 4; ++j) { ga[j] += 64; gb[j] += 64; }
    __builtin_amdgcn_s_waitcnt(0x0f70);   // vmcnt(0), lgkm/exp unconstrained
    __syncthreads();                      // tile 0 visible

    for (int kt = 0; kt < K / 64 - 1; ++kt) {
      const int nb = (kt + 1) & 1;
      unsigned short* dA = lA + nb * BUF;
      unsigned short* dB = lB + nb * BUF;
#pragma unroll
      for (int j = 0; j < 4; ++j) async_copy16(ga[j], dA + j * 2048);
#pragma unroll
      for (int j = 0; j < 4; ++j) async_copy16(gb[j], dB + j * 2048);
#pragma unroll
      for (int j = 0; j < 4; ++j) { ga[j] += 64; gb[j] += 64; }
      __builtin_amdgcn_s_waitcnt(0x0f70); // drain overlaps consumers' MFMA
      __syncthreads();
    }
    __syncthreads();                      // matches consumers' kt=63 barrier
    return;
  }

  // ---------------- consumer waves ----------------
  const int lane = tid & 63;
  const int wm = wid >> 1;                 // wave row (0..1)
  const int wn = wid & 1;                  // wave col (0..1)
  const int lm = lane & 31;
  const int half = lane >> 5;
  const int swz_f = (lm & 7) ^ ((lm >> 3) & 3);

  int aoff[2][4], boff[2][4];
#pragma unroll
  for (int mt = 0; mt < 2; ++mt) {
    int r = wm * 64 + mt * 32 + lm;
#pragma unroll
    for (int ks = 0; ks < 4; ++ks) {
      int c = ks * 2 + half;
      aoff[mt][ks] = r * 64 + ((c ^ swz_f) * 8);
    }
  }
#pragma unroll
  for (int nt = 0; nt < 2; ++nt) {
    int r = wn * 64 + nt * 32 + lm;
#pragma unroll
    for (int ks = 0; ks < 4; ++ks) {
      int c = ks * 2 + half;
      boff[nt][ks] = r * 64 + ((c ^ swz_f) * 8);
    }
  }

  f32x16 acc[2][2];
#pragma unroll
  for (int mt = 0; mt < 2; ++mt)
#pragma unroll
    for (int nt = 0; nt < 2; ++nt)
#pragma unroll
      for (int i = 0; i < 16; ++i) acc[mt][nt][i] = 0.f;

  __syncthreads();                        // wait for tile 0

  for (int kt = 0; kt < K / 64; ++kt) {
    const unsigned short* as = As + (kt & 1) * BUF;
    const unsigned short* bs = Bs + (kt & 1) * BUF;
#pragma unroll
    for (int ks = 0; ks < 4; ++ks) {
      bf16x8 af[2], bfr[2];
#pragma unroll
      for (int mt = 0; mt < 2; ++mt) af[mt] = *(const bf16x8*)(as + aoff[mt][ks]);
#pragma unroll
      for (int nt = 0; nt < 2; ++nt) bfr[nt] = *(const bf16x8*)(bs + boff[nt][ks]);
#pragma unroll
      for (int mt = 0; mt < 2; ++mt)
#pragma unroll
        for (int nt = 0; nt < 2; ++nt)
          acc[mt][nt] = __builtin_amdgcn_mfma_f32_32x32x16_bf16(af[mt], bfr[nt],
                                                                acc[mt][nt], 0, 0, 0);
    }
    __syncthreads();                      // cheap: no outstanding VMEM here
  }

  // epilogue: 32x32 C/D layout col=lane&31, row=(reg&3)+8*(reg>>2)+4*(lane>>5)
#pragma unroll
  for (int nt = 0; nt < 2; ++nt) {
    const int col = nBase + wn * 64 + nt * 32 + lm;
    const float bc = bias[col];
#pragma unroll
    for (int mt = 0; mt < 2; ++mt) {
      const int row0 = mBase + wm * 64 + mt * 32 + 4 * half;
      float* cp = C + (size_t)row0 * N + col;
#pragma unroll
      for (int reg = 0; reg < 16; ++reg) {
        int row = (reg & 3) + 8 * (reg >> 2);
        cp[(size_t)row * N] = acc[mt][nt][reg] + bc;
      }
    }
  }
}

// ---------------- launch ----------------
extern "C" void kernel_launch(void* const* d_in, const int* in_sizes, int n_in,
                              void* d_out, int out_size, void* d_ws, size_t ws_size,
                              hipStream_t stream) {
  const float* x        = (const float*)d_in[0];
  const float* W        = (const float*)d_in[1];
  const float* b        = (const float*)d_in[2];
  const float* A        = (const float*)d_in[3];
  const float* Bm       = (const float*)d_in[4];
  const float* in_signs = (const float*)d_in[5];
  const float* out_signs= (const float*)d_in[6];
  const int*   in_perm  = (const int*)d_in[7];
  const int*   out_perm = (const int*)d_in[9];
  float* out = (float*)d_out;

  char* ws = (char*)d_ws;
  unsigned short* x_bf = (unsigned short*)ws;                       // 64 MiB
  unsigned short* weff = (unsigned short*)(ws + (size_t)67108864);  // 32 MiB
  float* A2  = (float*)(ws + (size_t)67108864 + (size_t)33554432);
  float* B2t = A2 + RANK * DDIM;

  convert_x_kernel<<<16384, 256, 0, stream>>>((const float4*)x, (u16x8*)x_bf);
  srht_fold_kernel<<<16, 1024, 0, stream>>>(A, Bm, in_signs, out_signs, in_perm, out_perm,
                                            A2, B2t);
  weff_kernel<<<8192, 256, 0, stream>>>((const float4*)W, A2, B2t, (u16x8*)weff);
  gemm_bt_kernel<<<2048, 512, 0, stream>>>(x_bf, weff, b, out);
}

// Round 5
// 577.119 us; speedup vs baseline: 1.0761x; 1.0761x over previous
//
#include <hip/hip_runtime.h>
#include <stdint.h>
#include <stddef.h>

// Problem constants
#define DDIM 4096
#define MROWS 8192          // 4 * 2048
#define RANK 8

typedef __attribute__((ext_vector_type(8))) short bf16x8;    // 8 bf16 = 4 VGPRs
typedef __attribute__((ext_vector_type(16))) float f32x16;
typedef __attribute__((ext_vector_type(8))) unsigned short u16x8;

// RNE float -> bf16 bits
__device__ __forceinline__ unsigned short f2bf(float f) {
  union { float f; unsigned int u; } c; c.f = f;
  unsigned int u = c.u + 0x7fffu + ((c.u >> 16) & 1u);
  return (unsigned short)(u >> 16);
}

// ---------------- Kernel 1: x fp32 -> bf16 (32B load / 16B store per thread) ----
__global__ void convert_x_kernel(const float4* __restrict__ x, u16x8* __restrict__ out) {
  int idx = blockIdx.x * 256 + threadIdx.x;
  float4 v0 = x[2 * idx];
  float4 v1 = x[2 * idx + 1];
  u16x8 o;
  o[0] = f2bf(v0.x); o[1] = f2bf(v0.y); o[2] = f2bf(v0.z); o[3] = f2bf(v0.w);
  o[4] = f2bf(v1.x); o[5] = f2bf(v1.y); o[6] = f2bf(v1.z); o[7] = f2bf(v1.w);
  out[idx] = o;
}

// ---------------- Kernel 2: fold SRHT into A2 / B2t via FWHT (1024 thr) --------
__global__ __launch_bounds__(1024) void srht_fold_kernel(
    const float* __restrict__ A, const float* __restrict__ Bm,
    const float* __restrict__ in_signs, const float* __restrict__ out_signs,
    const int* __restrict__ in_perm, const int* __restrict__ out_perm,
    float* __restrict__ A2, float* __restrict__ B2t) {
  __shared__ float buf[DDIM];
  const int tid = threadIdx.x;
  const int b = blockIdx.x;
  if (b < RANK) {
    const int r = b;
    for (int j = tid; j < DDIM; j += 1024) {
      int p = in_perm[j];
      buf[j] = in_signs[p] * A[r * DDIM + p];
    }
  } else {
    const int r = b - RANK;
    for (int j = tid; j < DDIM; j += 1024) {
      int p = out_perm[j];
      buf[j] = out_signs[p] * Bm[p * RANK + r];
    }
  }
  __syncthreads();
  for (int h = 1; h < DDIM; h <<= 1) {
    for (int p = tid; p < DDIM / 2; p += 1024) {
      int j = p & (h - 1);
      int i0 = ((p - j) << 1) + j;
      int i1 = i0 + h;
      float a = buf[i0], c = buf[i1];
      buf[i0] = a + c;
      buf[i1] = a - c;
    }
    __syncthreads();
  }
  const float scale = (b < RANK) ? (1.0f / 64.0f) : (2.0f / 64.0f);  // 2/64 folds SCALE
  float* dst = (b < RANK) ? (A2 + b * DDIM) : (B2t + (b - RANK) * DDIM);
  for (int j = tid; j < DDIM; j += 1024) dst[j] = buf[j] * scale;
}

// ---------------- Kernel 3: Weff = bf16(W + B2*A2) ----------------
__global__ void weff_kernel(const float4* __restrict__ W, const float* __restrict__ A2,
                            const float* __restrict__ B2t, u16x8* __restrict__ Weff) {
  int idx = blockIdx.x * 256 + threadIdx.x;  // 8-float groups: 4096*512
  int o = idx >> 9;                          // output row
  int c8 = idx & 511;                        // 8-float group within row
  float4 w0 = W[2 * idx];
  float4 w1 = W[2 * idx + 1];
#pragma unroll
  for (int r = 0; r < RANK; ++r) {
    float s = B2t[r * DDIM + o];
    const float4* av = (const float4*)(A2 + r * DDIM) + 2 * c8;
    float4 a0 = av[0], a1 = av[1];
    w0.x += s * a0.x; w0.y += s * a0.y; w0.z += s * a0.z; w0.w += s * a0.w;
    w1.x += s * a1.x; w1.y += s * a1.y; w1.z += s * a1.z; w1.w += s * a1.w;
  }
  u16x8 u;
  u[0] = f2bf(w0.x); u[1] = f2bf(w0.y); u[2] = f2bf(w0.z); u[3] = f2bf(w0.w);
  u[4] = f2bf(w1.x); u[5] = f2bf(w1.y); u[6] = f2bf(w1.z); u[7] = f2bf(w1.w);
  Weff[idx] = u;
}

// ---------------- Kernel 4: C = A * B^T + bias ----------------
// Block tile 256x128 (BK=64), 4 waves, wave tile 128x64 = 4x2 of 32x32x16 MFMA.
// Rationale (R4 post-mortem): LDS read pipe was the limiter (1:1 b128:MFMA =
// 12 vs 8 CU-cyc). 4x2 wave tile -> 6 reads per 8 MFMAs: LDS ~295k vs MFMA
// ~262k cyc/CU, near-balanced. Homogeneous R3-style loop (producer split
// regressed). Swizzle swz(r) = (r&7)^((r>>3)&3), conflict-free (R3-verified).
__device__ __forceinline__ void async_copy16(const unsigned short* g, unsigned short* l) {
  __builtin_amdgcn_global_load_lds(
      (const __attribute__((address_space(1))) unsigned int*)g,
      (__attribute__((address_space(3))) unsigned int*)l, 16, 0, 0);
}

__global__ __launch_bounds__(256, 2) void gemm_bt_kernel(
    const unsigned short* __restrict__ Ab,   // M x K bf16 (x)
    const unsigned short* __restrict__ Bb,   // N x K bf16 (Weff)
    const float* __restrict__ bias,
    float* __restrict__ C) {                 // M x N fp32
  constexpr int K = 4096, N = 4096;
  __shared__ unsigned short As[256 * 64];    // 32 KB
  __shared__ unsigned short Bs[128 * 64];    // 16 KB

  const int tid = threadIdx.x;
  const int pid = blockIdx.x;

  // grouped ordering for L2 reuse (GROUP_M = 8); grid = 32 m-blocks x 32 n-blocks
  const int GRID_N = 32;
  const int grpsz = 8 * GRID_N;            // 256
  const int group = pid / grpsz;
  const int lpid = pid % grpsz;
  const int m_blk = group * 8 + (lpid & 7);
  const int n_blk = lpid >> 3;
  const int mBase = m_blk * 256;
  const int nBase = n_blk * 128;

  // --- staging addressing: A = 8 rounds, B = 4 rounds of 256 thr x 16B ---
  const int sr = tid >> 3;                               // row within 32-row round
  const int swz_s = (sr & 7) ^ ((sr >> 3) & 3);
  const int sc = (tid & 7) ^ swz_s;                      // global 16B chunk to fetch
  const unsigned short* ga[8];
  const unsigned short* gb[4];
#pragma unroll
  for (int j = 0; j < 8; ++j)
    ga[j] = Ab + (size_t)(mBase + j * 32 + sr) * K + sc * 8;
#pragma unroll
  for (int j = 0; j < 4; ++j)
    gb[j] = Bb + (size_t)(nBase + j * 32 + sr) * K + sc * 8;
  unsigned short* lA = As + tid * 8;
  unsigned short* lB = Bs + tid * 8;

  // --- fragment addressing (32x32x16: m/n = lane&31, k = (lane>>5)*8 + j) ---
  const int lane = tid & 63;
  const int wid = tid >> 6;
  const int wm = wid >> 1;                 // 0..1 -> M half (128 rows each)
  const int wn = wid & 1;                  // 0..1 -> N half (64 cols each)
  const int lm = lane & 31;
  const int half = lane >> 5;
  const int swz_f = (lm & 7) ^ ((lm >> 3) & 3);

  int aoff[4][4], boff[2][4];
#pragma unroll
  for (int mt = 0; mt < 4; ++mt) {
    int r = wm * 128 + mt * 32 + lm;
#pragma unroll
    for (int ks = 0; ks < 4; ++ks) {
      int c = ks * 2 + half;
      aoff[mt][ks] = r * 64 + ((c ^ swz_f) * 8);
    }
  }
#pragma unroll
  for (int nt = 0; nt < 2; ++nt) {
    int r = wn * 64 + nt * 32 + lm;
#pragma unroll
    for (int ks = 0; ks < 4; ++ks) {
      int c = ks * 2 + half;
      boff[nt][ks] = r * 64 + ((c ^ swz_f) * 8);
    }
  }

  f32x16 acc[4][2];
#pragma unroll
  for (int mt = 0; mt < 4; ++mt)
#pragma unroll
    for (int nt = 0; nt < 2; ++nt)
#pragma unroll
      for (int i = 0; i < 16; ++i) acc[mt][nt][i] = 0.f;

  for (int kt = 0; kt < K / 64; ++kt) {
#pragma unroll
    for (int j = 0; j < 8; ++j) async_copy16(ga[j], lA + j * 2048);
#pragma unroll
    for (int j = 0; j < 4; ++j) async_copy16(gb[j], lB + j * 2048);
#pragma unroll
    for (int j = 0; j < 8; ++j) ga[j] += 64;
#pragma unroll
    for (int j = 0; j < 4; ++j) gb[j] += 64;
    __syncthreads();   // drains vmcnt: staged tile visible
#pragma unroll
    for (int ks = 0; ks < 4; ++ks) {
      bf16x8 af[4], bfr[2];
#pragma unroll
      for (int mt = 0; mt < 4; ++mt) af[mt] = *(const bf16x8*)(As + aoff[mt][ks]);
#pragma unroll
      for (int nt = 0; nt < 2; ++nt) bfr[nt] = *(const bf16x8*)(Bs + boff[nt][ks]);
#pragma unroll
      for (int mt = 0; mt < 4; ++mt)
#pragma unroll
        for (int nt = 0; nt < 2; ++nt)
          acc[mt][nt] = __builtin_amdgcn_mfma_f32_32x32x16_bf16(af[mt], bfr[nt],
                                                                acc[mt][nt], 0, 0, 0);
    }
    __syncthreads();   // compute done before next stage overwrites
  }

  // epilogue: 32x32 C/D layout col=lane&31, row=(reg&3)+8*(reg>>2)+4*(lane>>5)
#pragma unroll
  for (int nt = 0; nt < 2; ++nt) {
    const int col = nBase + wn * 64 + nt * 32 + lm;
    const float bc = bias[col];
#pragma unroll
    for (int mt = 0; mt < 4; ++mt) {
      const int row0 = mBase + wm * 128 + mt * 32 + 4 * half;
      float* cp = C + (size_t)row0 * N + col;
#pragma unroll
      for (int reg = 0; reg < 16; ++reg) {
        int row = (reg & 3) + 8 * (reg >> 2);
        cp[(size_t)row * N] = acc[mt][nt][reg] + bc;
      }
    }
  }
}

// ---------------- launch ----------------
extern "C" void kernel_launch(void* const* d_in, const int* in_sizes, int n_in,
                              void* d_out, int out_size, void* d_ws, size_t ws_size,
                              hipStream_t stream) {
  const float* x        = (const float*)d_in[0];
  const float* W        = (const float*)d_in[1];
  const float* b        = (const float*)d_in[2];
  const float* A        = (const float*)d_in[3];
  const float* Bm       = (const float*)d_in[4];
  const float* in_signs = (const float*)d_in[5];
  const float* out_signs= (const float*)d_in[6];
  const int*   in_perm  = (const int*)d_in[7];
  const int*   out_perm = (const int*)d_in[9];
  float* out = (float*)d_out;

  char* ws = (char*)d_ws;
  unsigned short* x_bf = (unsigned short*)ws;                       // 64 MiB
  unsigned short* weff = (unsigned short*)(ws + (size_t)67108864);  // 32 MiB
  float* A2  = (float*)(ws + (size_t)67108864 + (size_t)33554432);
  float* B2t = A2 + RANK * DDIM;

  convert_x_kernel<<<16384, 256, 0, stream>>>((const float4*)x, (u16x8*)x_bf);
  srht_fold_kernel<<<16, 1024, 0, stream>>>(A, Bm, in_signs, out_signs, in_perm, out_perm,
                                            A2, B2t);
  weff_kernel<<<8192, 256, 0, stream>>>((const float4*)W, A2, B2t, (u16x8*)weff);
  gemm_bt_kernel<<<1024, 256, 0, stream>>>(x_bf, weff, b, out);
}